// Round 19
// baseline (455.216 us; speedup 1.0000x reference)
//
#include <hip/hip_runtime.h>
#include <hip/hip_bf16.h>
#include <math.h>

#define D_MODEL 1024
#define HS 2048
#define HE 1024
#define NEXP 8
#define NTOK 4096
#define NSLOT 8192

typedef __attribute__((ext_vector_type(4))) float f32x4;
typedef __attribute__((ext_vector_type(8))) short bf16x8;

__device__ __forceinline__ short f2b(float f) {
  __hip_bfloat16 h = __float2bfloat16(f);
  return *reinterpret_cast<short*>(&h);
}
__device__ __forceinline__ float b2f(short s) {
  return __bfloat162float(*reinterpret_cast<__hip_bfloat16*>(&s));
}

__device__ __forceinline__ void gl_lds16(const short* g, short* l) {
  __builtin_amdgcn_global_load_lds(
      (const __attribute__((address_space(1))) void*)g,
      (__attribute__((address_space(3))) void*)l, 16, 0, 0);
}

// ---------------- merged transpose prep (2 tiles per block) ----------------
__device__ __forceinline__ void tr_tile(const float* __restrict__ in,
                                        short* __restrict__ out, int R, int C,
                                        int bx, int by, int bz, int rmap,
                                        float (*tile)[69], int t) {
  const int c0 = bx * 64;
  const int r0 = by * 64;
  const size_t bo = (size_t)bz * R * C;
  const int lr = t >> 4;
  const int lc4 = (t & 15) * 4;
#pragma unroll
  for (int i = 0; i < 4; i++) {
    const float4 v = *(const float4*)&in[bo + (size_t)(r0 + lr + i * 16) * C + c0 + lc4];
    tile[lc4 + 0][lr + i * 16] = v.x;
    tile[lc4 + 1][lr + i * 16] = v.y;
    tile[lc4 + 2][lr + i * 16] = v.z;
    tile[lc4 + 3][lr + i * 16] = v.w;
  }
  __syncthreads();
#pragma unroll
  for (int i = 0; i < 4; i++) {
    const int oc = (t >> 4) + i * 16;
    const int or4 = (t & 15) * 4;
    short4 o;
    o.x = f2b(tile[oc][or4 + 0]);
    o.y = f2b(tile[oc][or4 + 1]);
    o.z = f2b(tile[oc][or4 + 2]);
    o.w = f2b(tile[oc][or4 + 3]);
    const int c = c0 + oc;
    size_t orow;
    if (rmap == 0) orow = bo + (size_t)c * R;
    else orow = (size_t)((c >> 5) * 64 + (rmap == 2 ? 32 : 0) + (c & 31)) * R;
    *(short4*)&out[orow + r0 + or4] = o;
  }
}

__device__ __forceinline__ void tr_dispatch(
    int id, const float* w1, const float* w3, const float* w2, const float* W1e,
    const float* W2e, short* w13I, short* w2T, short* W1eT, short* W2eT,
    float (*tile)[69], int t) {
  if (id < 1024) {
    const int z = id >> 9, rem = id & 511;
    tr_tile(z ? w3 : w1, w13I, D_MODEL, HS, rem & 31, rem >> 5, 0, z ? 2 : 1, tile, t);
  } else if (id < 1536) {
    const int rem = id - 1024;
    tr_tile(w2, w2T, HS, D_MODEL, rem & 15, rem >> 4, 0, 0, tile, t);
  } else {
    const int rem = id - 1536;
    const int z = rem >> 8, r2 = rem & 255;
    if (z < 8)
      tr_tile(W1e, W1eT, D_MODEL, HE, r2 & 15, r2 >> 4, z, 0, tile, t);
    else
      tr_tile(W2e, W2eT, HE, D_MODEL, r2 & 15, r2 >> 4, z - 8, 0, tile, t);
  }
}

__global__ __launch_bounds__(256) void tr_all(
    const float* __restrict__ w1, const float* __restrict__ w3,
    const float* __restrict__ w2, const float* __restrict__ W1e,
    const float* __restrict__ W2e, short* __restrict__ w13I,
    short* __restrict__ w2T, short* __restrict__ W1eT, short* __restrict__ W2eT) {
  __shared__ float tile[64][69];
  const int t = threadIdx.x;
  tr_dispatch(blockIdx.x * 2, w1, w3, w2, W1e, W2e, w13I, w2T, W1eT, W2eT, tile, t);
  __syncthreads();
  tr_dispatch(blockIdx.x * 2 + 1, w1, w3, w2, W1e, W2e, w13I, w2T, W1eT, W2eT, tile, t);
}

// ------- router + x->bf16 convert fused -------
__global__ __launch_bounds__(256) void router_kernel(
    const float* __restrict__ x, const float* __restrict__ temb,
    const float* __restrict__ rw, const float* __restrict__ rbias,
    short* __restrict__ xb, int* __restrict__ topk, float* __restrict__ gates) {
  const int t = (blockIdx.x * 256 + threadIdx.x) >> 6;
  const int lane = threadIdx.x & 63;
  const float* xr = x + (size_t)t * D_MODEL;
  const float* tr = temb + (size_t)(t >> 10) * D_MODEL;  // T=1024
  float acc[NEXP] = {};
#pragma unroll
  for (int i = 0; i < 4; i++) {
    const int j = i * 256 + lane * 4;
    const float4 xv = *(const float4*)&xr[j];
    const float4 tv = *(const float4*)&tr[j];
    short4 o;
    o.x = f2b(xv.x); o.y = f2b(xv.y); o.z = f2b(xv.z); o.w = f2b(xv.w);
    *(short4*)&xb[(size_t)t * D_MODEL + j] = o;
    const float* wx = rw + (size_t)j * NEXP;
    const float* wt = rw + (size_t)(D_MODEL + j) * NEXP;
    const float xa[4] = {xv.x, xv.y, xv.z, xv.w};
    const float ta[4] = {tv.x, tv.y, tv.z, tv.w};
#pragma unroll
    for (int u = 0; u < 4; u++)
#pragma unroll
      for (int e = 0; e < NEXP; e++)
        acc[e] += xa[u] * wx[u * NEXP + e] + ta[u] * wt[u * NEXP + e];
  }
#pragma unroll
  for (int off = 32; off; off >>= 1)
#pragma unroll
    for (int e = 0; e < NEXP; e++) acc[e] += __shfl_xor(acc[e], off);
  if (lane == 0) {
    float s[NEXP], sel[NEXP];
#pragma unroll
    for (int e = 0; e < NEXP; e++) {
      s[e] = 1.f / (1.f + expf(-acc[e]));
      sel[e] = s[e] + rbias[e];
    }
    int i0 = 0;
#pragma unroll
    for (int e = 1; e < NEXP; e++) if (sel[e] > sel[i0]) i0 = e;
    int i1 = (i0 == 0) ? 1 : 0;
#pragma unroll
    for (int e = 0; e < NEXP; e++) if (e != i0 && sel[e] > sel[i1]) i1 = e;
    float s0 = s[i0], s1 = s[i1], den = s0 + s1;
    float g0, g1;
    if (den > 1e-9f) { g0 = s0 / (den + 1e-9f); g1 = s1 / (den + 1e-9f); }
    else { g0 = 0.5f; g1 = 0.5f; }
    topk[t * 2] = i0; topk[t * 2 + 1] = i1;
    gates[t * 2] = g0; gates[t * 2 + 1] = g1;
  }
}

// ------- grouping + work-queue init (counters re-zeroed every call) -------
__global__ __launch_bounds__(1024) void group_kernel(const int* __restrict__ topk,
                                                     int* __restrict__ perm,
                                                     int* __restrict__ offs,
                                                     int* __restrict__ te,
                                                     int* __restrict__ tm,
                                                     int* __restrict__ ntile,
                                                     int* __restrict__ qcnt) {
  __shared__ int cnt[NEXP], cur[NEXP];
  const int t = threadIdx.x;
  if (t < NEXP) cnt[t] = 0;
  if (t < 2) qcnt[t] = 0;  // work-stealing cursors for k1/k2
  __syncthreads();
  int mye[8];
#pragma unroll
  for (int i = 0; i < 8; i++) {
    mye[i] = topk[i * 1024 + t];
    atomicAdd(&cnt[mye[i]], 1);
  }
  __syncthreads();
  if (t == 0) {
    int a = 0;
    for (int e = 0; e < NEXP; e++) { offs[e] = a; cur[e] = a; a += cnt[e]; }
    offs[NEXP] = a;
    int nt = 0;
    for (int e = 0; e < NEXP; e++)
      for (int m0 = 0; m0 < cnt[e]; m0 += 128) { te[nt] = e; tm[nt] = m0; nt++; }
    ntile[0] = nt;  // <= 72
  }
  __syncthreads();
#pragma unroll
  for (int i = 0; i < 8; i++) {
    int pos = atomicAdd(&cur[mye[i]], 1);
    perm[pos] = i * 1024 + t;
  }
}

// ====== KERNEL-1: work-stealing persistent. Jobs 0..1599: G1(<1024)/GG1 ======
// Body = R15-proven BK=64/64KiB/conc-2 template.
__global__ __launch_bounds__(256, 2) void moe_k1(
    const short* __restrict__ xb, const short* __restrict__ w13I,
    const short* __restrict__ W1eT, short* __restrict__ ubuf,
    short* __restrict__ hexpb, const int* __restrict__ perm,
    const int* __restrict__ offs, const int* __restrict__ te,
    const int* __restrict__ tm, const int* __restrict__ ntile,
    int* __restrict__ qcnt) {
  extern __shared__ short lds[];
  __shared__ int sjob;
  const int td = threadIdx.x;

  const int l = td & 63;
  const int wv = td >> 6;
  const int wm = (wv >> 1) * 64, wn = (wv & 1) * 64;
  const int lr = l & 15;
  const int swzk0 = ((0 + (l >> 4) * 16) ^ ((l & 7) << 4)) >> 1;
  const int swzk1 = ((64 + (l >> 4) * 16) ^ ((l & 7) << 4)) >> 1;
  const int srow = td >> 3;
  const int colsw8 = ((td & 7) ^ (srow & 7)) * 8;

#define K1STAGE(t_, b_)                                                    \
  do {                                                                     \
    gl_lds16(ap[0] + (t_) * 64, lds + (b_) * 16384 + td * 8);              \
    gl_lds16(ap[1] + (t_) * 64, lds + (b_) * 16384 + 2048 + td * 8);       \
    gl_lds16(ap[2] + (t_) * 64, lds + (b_) * 16384 + 4096 + td * 8);       \
    gl_lds16(ap[3] + (t_) * 64, lds + (b_) * 16384 + 6144 + td * 8);       \
    gl_lds16(bp[0] + (t_) * 64, lds + (b_) * 16384 + 8192 + td * 8);       \
    gl_lds16(bp[1] + (t_) * 64, lds + (b_) * 16384 + 10240 + td * 8);      \
    gl_lds16(bp[2] + (t_) * 64, lds + (b_) * 16384 + 12288 + td * 8);      \
    gl_lds16(bp[3] + (t_) * 64, lds + (b_) * 16384 + 14336 + td * 8);      \
  } while (0)
#define LDA1(mf_, swz_) (*(const bf16x8*)&Ah[(unsigned)(((mf_)*16 + lr) * 64) + (swz_)])
#define LDB1(nf_, swz_) (*(const bf16x8*)&Bh[(unsigned)(((nf_)*16 + lr) * 64) + (swz_)])
#define MM1(mf_, a_)                                                                   \
  acc[mf_][0] = __builtin_amdgcn_mfma_f32_16x16x32_bf16(a_, b0, acc[mf_][0], 0, 0, 0); \
  acc[mf_][1] = __builtin_amdgcn_mfma_f32_16x16x32_bf16(a_, b1, acc[mf_][1], 0, 0, 0); \
  acc[mf_][2] = __builtin_amdgcn_mfma_f32_16x16x32_bf16(a_, b2, acc[mf_][2], 0, 0, 0); \
  acc[mf_][3] = __builtin_amdgcn_mfma_f32_16x16x32_bf16(a_, b3, acc[mf_][3], 0, 0, 0)

  for (;;) {
    if (td == 0) sjob = atomicAdd(&qcnt[0], 1);
    __syncthreads();
    const int id = sjob;
    if (id >= 1600) break;

    const bool isG1 = id < 1024;
    int m_panel = 0, n_panel = 0, m0 = 0, rbeg = 0, rend = 0, bxn = 0;
    const short* Bb;
    bool valid = true;
    if (isG1) {
      const int xcd = id & 7, w = id >> 3;
      n_panel = xcd * 4 + (w >> 5);
      m_panel = w & 31;
      Bb = w13I + (size_t)n_panel * 128 * 1024;
    } else {
      const int g = id - 1024;
      const int ty = g >> 3;
      valid = (ty < ntile[0]);
      bxn = g & 7;
      const int e = valid ? te[ty] : 0;
      m0 = valid ? tm[ty] : 0;
      rbeg = offs[e]; rend = offs[e + 1];
      Bb = W1eT + ((size_t)e * 1024 + bxn * 128) * 1024;
    }
    if (!valid) continue;  // uniform

    const short* ap[4];
    const short* bp[4];
#pragma unroll
    for (int u = 0; u < 4; u++) {
      const int trow = u * 32 + srow;
      int grow;
      if (isG1) grow = m_panel * 128 + trow;
      else grow = perm[min(rbeg + m0 + trow, rend - 1)] >> 1;
      ap[u] = xb + (size_t)grow * 1024 + colsw8;
      bp[u] = Bb + (size_t)trow * 1024 + colsw8;
    }

    f32x4 acc[4][4] = {};

    K1STAGE(0, 0);
    for (int t = 0; t < 16; ++t) {
      const int p = t & 1, q = p ^ 1;
      const short* Ah = lds + p * 16384 + wm * 64;
      const short* Bh = lds + p * 16384 + 8192 + wn * 64;
      if (t < 15) {
        K1STAGE(t + 1, q);
        asm volatile("s_waitcnt vmcnt(8)" ::: "memory");
      } else {
        asm volatile("s_waitcnt vmcnt(0)" ::: "memory");
      }
      __builtin_amdgcn_s_barrier();
      {
        bf16x8 b0, b1, b2, b3, a0, a1, a2, a3;
        b0 = LDB1(0, swzk0); b1 = LDB1(1, swzk0); b2 = LDB1(2, swzk0); b3 = LDB1(3, swzk0);
        a0 = LDA1(0, swzk0); a1 = LDA1(1, swzk0); a2 = LDA1(2, swzk0); a3 = LDA1(3, swzk0);
        __builtin_amdgcn_s_setprio(1);
        MM1(0, a0); MM1(1, a1); MM1(2, a2); MM1(3, a3);
        __builtin_amdgcn_s_setprio(0);
        b0 = LDB1(0, swzk1); b1 = LDB1(1, swzk1); b2 = LDB1(2, swzk1); b3 = LDB1(3, swzk1);
        a0 = LDA1(0, swzk1); a1 = LDA1(1, swzk1); a2 = LDA1(2, swzk1); a3 = LDA1(3, swzk1);
        __builtin_amdgcn_s_setprio(1);
        MM1(0, a0); MM1(1, a1); MM1(2, a2); MM1(3, a3);
        __builtin_amdgcn_s_setprio(0);
      }
      __builtin_amdgcn_sched_barrier(0);
      __builtin_amdgcn_s_barrier();
    }

    const int rq = (l >> 4) * 4;
    if (isG1) {
#pragma unroll
      for (int mf = 0; mf < 4; mf++)
#pragma unroll
        for (int j = 0; j < 4; j++) {
          const int row = m_panel * 128 + wm + mf * 16 + rq + j;
          short* Up = ubuf + (size_t)row * HS + n_panel * 64 + (wn >> 1) + lr;
#pragma unroll
          for (int nf = 0; nf < 2; nf++) {
            const float a = acc[mf][nf][j];
            const float b = acc[mf][nf + 2][j];
            Up[nf * 16] = f2b(a / (1.f + expf(-a)) * b);
          }
        }
    } else {
#pragma unroll
      for (int mf = 0; mf < 4; mf++)
#pragma unroll
        for (int j = 0; j < 4; j++) {
          const int gi = rbeg + m0 + wm + mf * 16 + rq + j;
          if (gi < rend) {
            short* Cp = hexpb + (size_t)gi * HE + bxn * 128 + wn + lr;
#pragma unroll
            for (int nf = 0; nf < 4; nf++) {
              const float v = acc[mf][nf][j];
              Cp[nf * 16] = f2b(0.5f * v * (1.0f + erff(v * 0.70710678118654752f)));
            }
          }
        }
    }
  }
#undef K1STAGE
#undef LDA1
#undef LDB1
#undef MM1
}

// ====== KERNEL-2: work-stealing persistent. Jobs 0..831: G2(<256)/GG2 ======
__global__ __launch_bounds__(256, 2) void moe_k2(
    const short* __restrict__ ubuf, const short* __restrict__ w2T,
    const short* __restrict__ hexpb, const short* __restrict__ W2eT,
    float* __restrict__ out, short* __restrict__ yb,
    const int* __restrict__ perm, const int* __restrict__ offs,
    const float* __restrict__ gates, const int* __restrict__ te,
    const int* __restrict__ tm, const int* __restrict__ ntile,
    int* __restrict__ qcnt) {
  extern __shared__ short lds[];
  __shared__ int sjob;
  const int td = threadIdx.x;
  const int l = td & 63;
  const int wv = td >> 6;
  const int wm = (wv >> 1) * 64, wn = (wv & 1) * 64;
  const int lr = l & 15;
  const int swzk0 = ((0 + (l >> 4) * 16) ^ ((l & 7) << 4)) >> 1;
  const int swzk1 = ((64 + (l >> 4) * 16) ^ ((l & 7) << 4)) >> 1;
  const int srow = td >> 3;
  const int colsw8 = ((td & 7) ^ (srow & 7)) * 8;

#define K2STAGE(t_, b_)                                                    \
  do {                                                                     \
    gl_lds16(ap[0] + (t_) * 64, lds + (b_) * 16384 + td * 8);              \
    gl_lds16(ap[1] + (t_) * 64, lds + (b_) * 16384 + 2048 + td * 8);       \
    gl_lds16(ap[2] + (t_) * 64, lds + (b_) * 16384 + 4096 + td * 8);       \
    gl_lds16(ap[3] + (t_) * 64, lds + (b_) * 16384 + 6144 + td * 8);       \
    gl_lds16(bp[0] + (t_) * 64, lds + (b_) * 16384 + 8192 + td * 8);       \
    gl_lds16(bp[1] + (t_) * 64, lds + (b_) * 16384 + 10240 + td * 8);      \
    gl_lds16(bp[2] + (t_) * 64, lds + (b_) * 16384 + 12288 + td * 8);      \
    gl_lds16(bp[3] + (t_) * 64, lds + (b_) * 16384 + 14336 + td * 8);      \
  } while (0)
#define LDA2(mf_, swz_) (*(const bf16x8*)&Ah[(unsigned)(((mf_)*16 + lr) * 64) + (swz_)])
#define LDB2(nf_, swz_) (*(const bf16x8*)&Bh[(unsigned)(((nf_)*16 + lr) * 64) + (swz_)])
#define MM2(mf_, a_)                                                                   \
  acc[mf_][0] = __builtin_amdgcn_mfma_f32_16x16x32_bf16(a_, b0, acc[mf_][0], 0, 0, 0); \
  acc[mf_][1] = __builtin_amdgcn_mfma_f32_16x16x32_bf16(a_, b1, acc[mf_][1], 0, 0, 0); \
  acc[mf_][2] = __builtin_amdgcn_mfma_f32_16x16x32_bf16(a_, b2, acc[mf_][2], 0, 0, 0); \
  acc[mf_][3] = __builtin_amdgcn_mfma_f32_16x16x32_bf16(a_, b3, acc[mf_][3], 0, 0, 0)

  for (;;) {
    if (td == 0) sjob = atomicAdd(&qcnt[1], 1);
    __syncthreads();
    const int id = sjob;
    if (id >= 832) break;

    const bool isG2 = id < 256;
    int m_panel = 0, n_panel = 0, m0 = 0, rbeg = 0, rend = 0, bxn = 0, NT, K;
    const short* A;
    const short* Bb;
    bool valid = true;
    if (isG2) {
      const int xcd = id & 7, slot = id >> 3;
      n_panel = slot & 7;
      m_panel = xcd * 4 + (slot >> 3);
      A = ubuf;
      K = HS; NT = 32;
      Bb = w2T + (size_t)n_panel * 128 * HS;
    } else {
      const int g = id - 256;
      const int ty = g >> 3;
      valid = (ty < ntile[0]);
      bxn = g & 7;
      const int e = valid ? te[ty] : 0;
      m0 = valid ? tm[ty] : 0;
      rbeg = offs[e]; rend = offs[e + 1];
      A = hexpb;
      K = HE; NT = 16;
      Bb = W2eT + ((size_t)e * 1024 + bxn * 128) * 1024;
    }
    if (!valid) continue;

    const short* ap[4];
    const short* bp[4];
#pragma unroll
    for (int u = 0; u < 4; u++) {
      const int trow = u * 32 + srow;
      int grow;
      if (isG2) grow = m_panel * 128 + trow;
      else grow = min(rbeg + m0 + trow, rend - 1);
      ap[u] = A + (size_t)grow * K + colsw8;
      bp[u] = Bb + (size_t)trow * K + colsw8;
    }

    f32x4 acc[4][4] = {};

    K2STAGE(0, 0);
    for (int t = 0; t < NT; ++t) {
      const int p = t & 1, q = p ^ 1;
      const short* Ah = lds + p * 16384 + wm * 64;
      const short* Bh = lds + p * 16384 + 8192 + wn * 64;
      if (t < NT - 1) {
        K2STAGE(t + 1, q);
        asm volatile("s_waitcnt vmcnt(8)" ::: "memory");
      } else {
        asm volatile("s_waitcnt vmcnt(0)" ::: "memory");
      }
      __builtin_amdgcn_s_barrier();
      {
        bf16x8 b0, b1, b2, b3, a0, a1, a2, a3;
        b0 = LDB2(0, swzk0); b1 = LDB2(1, swzk0); b2 = LDB2(2, swzk0); b3 = LDB2(3, swzk0);
        a0 = LDA2(0, swzk0); a1 = LDA2(1, swzk0); a2 = LDA2(2, swzk0); a3 = LDA2(3, swzk0);
        __builtin_amdgcn_s_setprio(1);
        MM2(0, a0); MM2(1, a1); MM2(2, a2); MM2(3, a3);
        __builtin_amdgcn_s_setprio(0);
        b0 = LDB2(0, swzk1); b1 = LDB2(1, swzk1); b2 = LDB2(2, swzk1); b3 = LDB2(3, swzk1);
        a0 = LDA2(0, swzk1); a1 = LDA2(1, swzk1); a2 = LDA2(2, swzk1); a3 = LDA2(3, swzk1);
        __builtin_amdgcn_s_setprio(1);
        MM2(0, a0); MM2(1, a1); MM2(2, a2); MM2(3, a3);
        __builtin_amdgcn_s_setprio(0);
      }
      __builtin_amdgcn_sched_barrier(0);
      __builtin_amdgcn_s_barrier();
    }

    const int rq = (l >> 4) * 4;
    if (isG2) {
#pragma unroll
      for (int mf = 0; mf < 4; mf++)
#pragma unroll
        for (int j = 0; j < 4; j++) {
          const int tok = m_panel * 128 + wm + mf * 16 + rq + j;
          float* Op = out + (size_t)tok * D_MODEL + n_panel * 128 + wn + lr;
#pragma unroll
          for (int nf = 0; nf < 4; nf++) Op[nf * 16] = acc[mf][nf][j];
        }
    } else {
#pragma unroll
      for (int mf = 0; mf < 4; mf++)
#pragma unroll
        for (int j = 0; j < 4; j++) {
          const int gi = rbeg + m0 + wm + mf * 16 + rq + j;
          if (gi < rend) {
            const int slot = perm[gi];
            const float g = gates[slot];
            short* Cp = yb + (size_t)slot * D_MODEL + bxn * 128 + wn + lr;
#pragma unroll
            for (int nf = 0; nf < 4; nf++) Cp[nf * 16] = f2b(g * acc[mf][nf][j]);
          }
        }
    }
  }
#undef K2STAGE
#undef LDA2
#undef LDB2
#undef MM2
}

// ---- final combine: out = (out(shared) + y0 + y1) / 3 ----
__global__ __launch_bounds__(256) void combine_kernel(float* __restrict__ out,
                                                      const short* __restrict__ yb) {
  const float inv3 = 1.0f / 3.0f;
#pragma unroll
  for (int rep = 0; rep < 2; rep++) {
    const int i = (rep * 2048 + blockIdx.x) * 256 + threadIdx.x;
    const int base = i * 4;
    const int tok = base >> 10;
    const int col = base & (D_MODEL - 1);
    float4 s = *(float4*)&out[base];
    const short4 y0 = *(const short4*)&yb[(size_t)(tok * 2) * D_MODEL + col];
    const short4 y1 = *(const short4*)&yb[(size_t)(tok * 2 + 1) * D_MODEL + col];
    s.x = (s.x + b2f(y0.x) + b2f(y1.x)) * inv3;
    s.y = (s.y + b2f(y0.y) + b2f(y1.y)) * inv3;
    s.z = (s.z + b2f(y0.z) + b2f(y1.z)) * inv3;
    s.w = (s.w + b2f(y0.w) + b2f(y1.w)) * inv3;
    *(float4*)&out[base] = s;
  }
}

// ---------------- launch ----------------
extern "C" void kernel_launch(void* const* d_in, const int* in_sizes, int n_in,
                              void* d_out, int out_size, void* d_ws, size_t ws_size,
                              hipStream_t stream) {
  const float* x = (const float*)d_in[0];
  const float* temb = (const float*)d_in[1];
  const float* rw = (const float*)d_in[2];
  const float* rbias = (const float*)d_in[3];
  const float* w1 = (const float*)d_in[4];
  const float* w3 = (const float*)d_in[5];
  const float* w2 = (const float*)d_in[6];
  const float* W1e = (const float*)d_in[7];
  const float* W2e = (const float*)d_in[8];
  float* out = (float*)d_out;

  const size_t MB = 1ull << 20;
  char* w = (char*)d_ws;
  short* xb    = (short*)(w + 0 * MB);
  short* w13I  = (short*)(w + 8 * MB);
  short* w2T   = (short*)(w + 16 * MB);
  short* W1eT  = (short*)(w + 20 * MB);
  short* W2eT  = (short*)(w + 36 * MB);
  short* ubuf  = (short*)(w + 52 * MB);
  short* hexpb = (short*)(w + 68 * MB);
  short* yb    = (short*)(w + 84 * MB);
  float* gates = (float*)(w + 100 * MB);
  int* topk    = (int*)(w + 100 * MB + 32 * 1024);
  int* perm    = (int*)(w + 100 * MB + 64 * 1024);
  int* meta    = (int*)(w + 100 * MB + 96 * 1024);
  int* offs    = meta;
  int* te      = meta + 16;
  int* tm      = meta + 128;
  int* ntile   = meta + 256;
  int* qcnt    = meta + 512;  // [0]=k1 cursor, [1]=k2 cursor (zeroed per call)

  hipFuncSetAttribute((const void*)&moe_k1,
                      hipFuncAttributeMaxDynamicSharedMemorySize, 65536);
  hipFuncSetAttribute((const void*)&moe_k2,
                      hipFuncAttributeMaxDynamicSharedMemorySize, 65536);

  // prep
  tr_all<<<2816, 256, 0, stream>>>(w1, w3, w2, W1e, W2e, w13I, w2T, W1eT, W2eT);
  router_kernel<<<NTOK / 4, 256, 0, stream>>>(x, temb, rw, rbias, xb, topk, gates);
  group_kernel<<<1, 1024, 0, stream>>>(topk, perm, offs, te, tm, ntile, qcnt);

  // kernel-1: 512 steal-slots over 1600 jobs (G1 1024 + GG1 576)
  moe_k1<<<512, 256, 65536, stream>>>(xb, w13I, W1eT, ubuf, hexpb, perm, offs,
                                      te, tm, ntile, qcnt);

  // kernel-2: 512 steal-slots over 832 jobs (G2 256 first [long], GG2 576)
  moe_k2<<<512, 256, 65536, stream>>>(ubuf, w2T, hexpb, W2eT, out, yb, perm,
                                      offs, gates, te, tm, ntile, qcnt);

  // combine
  combine_kernel<<<2048, 256, 0, stream>>>(out, yb);
}

// Round 20
// 223.872 us; speedup vs baseline: 2.0334x; 2.0334x over previous
//
#include <hip/hip_runtime.h>
#include <hip/hip_bf16.h>
#include <math.h>

#define D_MODEL 1024
#define HS 2048
#define HE 1024
#define NEXP 8
#define NTOK 4096
#define NSLOT 8192

typedef __attribute__((ext_vector_type(4))) float f32x4;
typedef __attribute__((ext_vector_type(8))) short bf16x8;

__device__ __forceinline__ short f2b(float f) {
  __hip_bfloat16 h = __float2bfloat16(f);
  return *reinterpret_cast<short*>(&h);
}
__device__ __forceinline__ float b2f(short s) {
  return __bfloat162float(*reinterpret_cast<__hip_bfloat16*>(&s));
}

__device__ __forceinline__ void gl_lds16(const short* g, short* l) {
  __builtin_amdgcn_global_load_lds(
      (const __attribute__((address_space(1))) void*)g,
      (__attribute__((address_space(3))) void*)l, 16, 0, 0);
}

// ---------------- merged transpose prep (2 tiles per block) ----------------
__device__ __forceinline__ void tr_tile(const float* __restrict__ in,
                                        short* __restrict__ out, int R, int C,
                                        int bx, int by, int bz, int rmap,
                                        float (*tile)[69], int t) {
  const int c0 = bx * 64;
  const int r0 = by * 64;
  const size_t bo = (size_t)bz * R * C;
  const int lr = t >> 4;
  const int lc4 = (t & 15) * 4;
#pragma unroll
  for (int i = 0; i < 4; i++) {
    const float4 v = *(const float4*)&in[bo + (size_t)(r0 + lr + i * 16) * C + c0 + lc4];
    tile[lc4 + 0][lr + i * 16] = v.x;
    tile[lc4 + 1][lr + i * 16] = v.y;
    tile[lc4 + 2][lr + i * 16] = v.z;
    tile[lc4 + 3][lr + i * 16] = v.w;
  }
  __syncthreads();
#pragma unroll
  for (int i = 0; i < 4; i++) {
    const int oc = (t >> 4) + i * 16;
    const int or4 = (t & 15) * 4;
    short4 o;
    o.x = f2b(tile[oc][or4 + 0]);
    o.y = f2b(tile[oc][or4 + 1]);
    o.z = f2b(tile[oc][or4 + 2]);
    o.w = f2b(tile[oc][or4 + 3]);
    const int c = c0 + oc;
    size_t orow;
    if (rmap == 0) orow = bo + (size_t)c * R;
    else orow = (size_t)((c >> 5) * 64 + (rmap == 2 ? 32 : 0) + (c & 31)) * R;
    *(short4*)&out[orow + r0 + or4] = o;
  }
}

__device__ __forceinline__ void tr_dispatch(
    int id, const float* w1, const float* w3, const float* w2, const float* W1e,
    const float* W2e, short* w13I, short* w2T, short* W1eT, short* W2eT,
    float (*tile)[69], int t) {
  if (id < 1024) {
    const int z = id >> 9, rem = id & 511;
    tr_tile(z ? w3 : w1, w13I, D_MODEL, HS, rem & 31, rem >> 5, 0, z ? 2 : 1, tile, t);
  } else if (id < 1536) {
    const int rem = id - 1024;
    tr_tile(w2, w2T, HS, D_MODEL, rem & 15, rem >> 4, 0, 0, tile, t);
  } else {
    const int rem = id - 1536;
    const int z = rem >> 8, r2 = rem & 255;
    if (z < 8)
      tr_tile(W1e, W1eT, D_MODEL, HE, r2 & 15, r2 >> 4, z, 0, tile, t);
    else
      tr_tile(W2e, W2eT, HE, D_MODEL, r2 & 15, r2 >> 4, z - 8, 0, tile, t);
  }
}

__global__ __launch_bounds__(256) void tr_all(
    const float* __restrict__ w1, const float* __restrict__ w3,
    const float* __restrict__ w2, const float* __restrict__ W1e,
    const float* __restrict__ W2e, short* __restrict__ w13I,
    short* __restrict__ w2T, short* __restrict__ W1eT, short* __restrict__ W2eT) {
  __shared__ float tile[64][69];
  const int t = threadIdx.x;
  tr_dispatch(blockIdx.x * 2, w1, w3, w2, W1e, W2e, w13I, w2T, W1eT, W2eT, tile, t);
  __syncthreads();
  tr_dispatch(blockIdx.x * 2 + 1, w1, w3, w2, W1e, W2e, w13I, w2T, W1eT, W2eT, tile, t);
}

// ------- router + x->bf16 convert fused -------
__global__ __launch_bounds__(256) void router_kernel(
    const float* __restrict__ x, const float* __restrict__ temb,
    const float* __restrict__ rw, const float* __restrict__ rbias,
    short* __restrict__ xb, int* __restrict__ topk, float* __restrict__ gates) {
  const int t = (blockIdx.x * 256 + threadIdx.x) >> 6;
  const int lane = threadIdx.x & 63;
  const float* xr = x + (size_t)t * D_MODEL;
  const float* tr = temb + (size_t)(t >> 10) * D_MODEL;  // T=1024
  float acc[NEXP] = {};
#pragma unroll
  for (int i = 0; i < 4; i++) {
    const int j = i * 256 + lane * 4;
    const float4 xv = *(const float4*)&xr[j];
    const float4 tv = *(const float4*)&tr[j];
    short4 o;
    o.x = f2b(xv.x); o.y = f2b(xv.y); o.z = f2b(xv.z); o.w = f2b(xv.w);
    *(short4*)&xb[(size_t)t * D_MODEL + j] = o;
    const float* wx = rw + (size_t)j * NEXP;
    const float* wt = rw + (size_t)(D_MODEL + j) * NEXP;
    const float xa[4] = {xv.x, xv.y, xv.z, xv.w};
    const float ta[4] = {tv.x, tv.y, tv.z, tv.w};
#pragma unroll
    for (int u = 0; u < 4; u++)
#pragma unroll
      for (int e = 0; e < NEXP; e++)
        acc[e] += xa[u] * wx[u * NEXP + e] + ta[u] * wt[u * NEXP + e];
  }
#pragma unroll
  for (int off = 32; off; off >>= 1)
#pragma unroll
    for (int e = 0; e < NEXP; e++) acc[e] += __shfl_xor(acc[e], off);
  if (lane == 0) {
    float s[NEXP], sel[NEXP];
#pragma unroll
    for (int e = 0; e < NEXP; e++) {
      s[e] = 1.f / (1.f + expf(-acc[e]));
      sel[e] = s[e] + rbias[e];
    }
    int i0 = 0;
#pragma unroll
    for (int e = 1; e < NEXP; e++) if (sel[e] > sel[i0]) i0 = e;
    int i1 = (i0 == 0) ? 1 : 0;
#pragma unroll
    for (int e = 0; e < NEXP; e++) if (e != i0 && sel[e] > sel[i1]) i1 = e;
    float s0 = s[i0], s1 = s[i1], den = s0 + s1;
    float g0, g1;
    if (den > 1e-9f) { g0 = s0 / (den + 1e-9f); g1 = s1 / (den + 1e-9f); }
    else { g0 = 0.5f; g1 = 0.5f; }
    topk[t * 2] = i0; topk[t * 2 + 1] = i1;
    gates[t * 2] = g0; gates[t * 2 + 1] = g1;
  }
}

// ------- grouping: hist + scan + fill + BM=128 tile table (ntile <= 72) ------
__global__ __launch_bounds__(1024) void group_kernel(const int* __restrict__ topk,
                                                     int* __restrict__ perm,
                                                     int* __restrict__ offs,
                                                     int* __restrict__ te,
                                                     int* __restrict__ tm,
                                                     int* __restrict__ ntile) {
  __shared__ int cnt[NEXP], cur[NEXP];
  const int t = threadIdx.x;
  if (t < NEXP) cnt[t] = 0;
  __syncthreads();
  int mye[8];
#pragma unroll
  for (int i = 0; i < 8; i++) {
    mye[i] = topk[i * 1024 + t];
    atomicAdd(&cnt[mye[i]], 1);
  }
  __syncthreads();
  if (t == 0) {
    int a = 0;
    for (int e = 0; e < NEXP; e++) { offs[e] = a; cur[e] = a; a += cnt[e]; }
    offs[NEXP] = a;
    int nt = 0;
    for (int e = 0; e < NEXP; e++)
      for (int m0 = 0; m0 < cnt[e]; m0 += 128) { te[nt] = e; tm[nt] = m0; nt++; }
    ntile[0] = nt;  // <= 72
  }
  __syncthreads();
#pragma unroll
  for (int i = 0; i < 8; i++) {
    int pos = atomicAdd(&cur[mye[i]], 1);
    perm[pos] = i * 1024 + t;
  }
}

// ====== KERNEL-1: static persistent 2-job (R18-proven). Jobs 0..1599 ======
__global__ __launch_bounds__(256, 2) void moe_k1(
    const short* __restrict__ xb, const short* __restrict__ w13I,
    const short* __restrict__ W1eT, short* __restrict__ ubuf,
    short* __restrict__ hexpb, const int* __restrict__ perm,
    const int* __restrict__ offs, const int* __restrict__ te,
    const int* __restrict__ tm, const int* __restrict__ ntile) {
  extern __shared__ short lds[];
  const int td = threadIdx.x;

  const int l = td & 63;
  const int wv = td >> 6;
  const int wm = (wv >> 1) * 64, wn = (wv & 1) * 64;
  const int lr = l & 15;
  const int swzk0 = ((0 + (l >> 4) * 16) ^ ((l & 7) << 4)) >> 1;
  const int swzk1 = ((64 + (l >> 4) * 16) ^ ((l & 7) << 4)) >> 1;
  const int srow = td >> 3;
  const int colsw8 = ((td & 7) ^ (srow & 7)) * 8;

#define K1STAGE(t_, b_)                                                    \
  do {                                                                     \
    gl_lds16(ap[0] + (t_) * 64, lds + (b_) * 16384 + td * 8);              \
    gl_lds16(ap[1] + (t_) * 64, lds + (b_) * 16384 + 2048 + td * 8);       \
    gl_lds16(ap[2] + (t_) * 64, lds + (b_) * 16384 + 4096 + td * 8);       \
    gl_lds16(ap[3] + (t_) * 64, lds + (b_) * 16384 + 6144 + td * 8);       \
    gl_lds16(bp[0] + (t_) * 64, lds + (b_) * 16384 + 8192 + td * 8);       \
    gl_lds16(bp[1] + (t_) * 64, lds + (b_) * 16384 + 10240 + td * 8);      \
    gl_lds16(bp[2] + (t_) * 64, lds + (b_) * 16384 + 12288 + td * 8);      \
    gl_lds16(bp[3] + (t_) * 64, lds + (b_) * 16384 + 14336 + td * 8);      \
  } while (0)
#define LDA1(mf_, swz_) (*(const bf16x8*)&Ah[(unsigned)(((mf_)*16 + lr) * 64) + (swz_)])
#define LDB1(nf_, swz_) (*(const bf16x8*)&Bh[(unsigned)(((nf_)*16 + lr) * 64) + (swz_)])
#define MM1(mf_, a_)                                                                   \
  acc[mf_][0] = __builtin_amdgcn_mfma_f32_16x16x32_bf16(a_, b0, acc[mf_][0], 0, 0, 0); \
  acc[mf_][1] = __builtin_amdgcn_mfma_f32_16x16x32_bf16(a_, b1, acc[mf_][1], 0, 0, 0); \
  acc[mf_][2] = __builtin_amdgcn_mfma_f32_16x16x32_bf16(a_, b2, acc[mf_][2], 0, 0, 0); \
  acc[mf_][3] = __builtin_amdgcn_mfma_f32_16x16x32_bf16(a_, b3, acc[mf_][3], 0, 0, 0)

  for (int job = 0; job < 2; ++job) {
    const int id = blockIdx.x + job * 800;
    const bool isG1 = id < 1024;
    int m_panel = 0, n_panel = 0, m0 = 0, rbeg = 0, rend = 0, bxn = 0;
    const short* Bb;
    bool valid = true;
    if (isG1) {
      const int xcd = id & 7, w = id >> 3;
      n_panel = xcd * 4 + (w >> 5);  // 32 n-panels (w13I 4096 rows / 128)
      m_panel = w & 31;
      Bb = w13I + (size_t)n_panel * 128 * 1024;
    } else {
      const int g = id - 1024;
      const int ty = g >> 3;
      valid = (ty < ntile[0]);
      bxn = g & 7;
      const int e = valid ? te[ty] : 0;
      m0 = valid ? tm[ty] : 0;
      rbeg = offs[e]; rend = offs[e + 1];
      Bb = W1eT + ((size_t)e * 1024 + bxn * 128) * 1024;
    }
    if (!valid) continue;  // uniform across block

    const short* ap[4];
    const short* bp[4];
#pragma unroll
    for (int u = 0; u < 4; u++) {
      const int trow = u * 32 + srow;
      int grow;
      if (isG1) grow = m_panel * 128 + trow;
      else grow = perm[min(rbeg + m0 + trow, rend - 1)] >> 1;
      ap[u] = xb + (size_t)grow * 1024 + colsw8;
      bp[u] = Bb + (size_t)trow * 1024 + colsw8;
    }

    f32x4 acc[4][4] = {};

    K1STAGE(0, 0);
    for (int t = 0; t < 16; ++t) {
      const int p = t & 1, q = p ^ 1;
      const short* Ah = lds + p * 16384 + wm * 64;
      const short* Bh = lds + p * 16384 + 8192 + wn * 64;
      if (t < 15) {
        K1STAGE(t + 1, q);
        asm volatile("s_waitcnt vmcnt(8)" ::: "memory");
      } else {
        asm volatile("s_waitcnt vmcnt(0)" ::: "memory");
      }
      __builtin_amdgcn_s_barrier();
      {
        bf16x8 b0, b1, b2, b3, a0, a1, a2, a3;
        b0 = LDB1(0, swzk0); b1 = LDB1(1, swzk0); b2 = LDB1(2, swzk0); b3 = LDB1(3, swzk0);
        a0 = LDA1(0, swzk0); a1 = LDA1(1, swzk0); a2 = LDA1(2, swzk0); a3 = LDA1(3, swzk0);
        __builtin_amdgcn_s_setprio(1);
        MM1(0, a0); MM1(1, a1); MM1(2, a2); MM1(3, a3);
        __builtin_amdgcn_s_setprio(0);
        b0 = LDB1(0, swzk1); b1 = LDB1(1, swzk1); b2 = LDB1(2, swzk1); b3 = LDB1(3, swzk1);
        a0 = LDA1(0, swzk1); a1 = LDA1(1, swzk1); a2 = LDA1(2, swzk1); a3 = LDA1(3, swzk1);
        __builtin_amdgcn_s_setprio(1);
        MM1(0, a0); MM1(1, a1); MM1(2, a2); MM1(3, a3);
        __builtin_amdgcn_s_setprio(0);
      }
      __builtin_amdgcn_sched_barrier(0);
      __builtin_amdgcn_s_barrier();
    }

    const int rq = (l >> 4) * 4;
    if (isG1) {
#pragma unroll
      for (int mf = 0; mf < 4; mf++)
#pragma unroll
        for (int j = 0; j < 4; j++) {
          const int row = m_panel * 128 + wm + mf * 16 + rq + j;
          short* Up = ubuf + (size_t)row * HS + n_panel * 64 + (wn >> 1) + lr;
#pragma unroll
          for (int nf = 0; nf < 2; nf++) {
            const float a = acc[mf][nf][j];
            const float b = acc[mf][nf + 2][j];
            Up[nf * 16] = f2b(a / (1.f + expf(-a)) * b);
          }
        }
    } else {
#pragma unroll
      for (int mf = 0; mf < 4; mf++)
#pragma unroll
        for (int j = 0; j < 4; j++) {
          const int gi = rbeg + m0 + wm + mf * 16 + rq + j;
          if (gi < rend) {
            short* Cp = hexpb + (size_t)gi * HE + bxn * 128 + wn + lr;
#pragma unroll
            for (int nf = 0; nf < 4; nf++) {
              const float v = acc[mf][nf][j];
              Cp[nf * 16] = f2b(0.5f * v * (1.0f + erff(v * 0.70710678118654752f)));
            }
          }
        }
    }
  }
#undef K1STAGE
#undef LDA1
#undef LDB1
#undef MM1
}

// ====== KERNEL-2: STATICALLY BALANCED persistent. Grid 544: blocks <256 run
// one G2 job (32 epochs); blocks >=256 run two GG2 jobs (2x16 epochs). ======
__global__ __launch_bounds__(256, 2) void moe_k2(
    const short* __restrict__ ubuf, const short* __restrict__ w2T,
    const short* __restrict__ hexpb, const short* __restrict__ W2eT,
    float* __restrict__ out, short* __restrict__ yb,
    const int* __restrict__ perm, const int* __restrict__ offs,
    const float* __restrict__ gates, const int* __restrict__ te,
    const int* __restrict__ tm, const int* __restrict__ ntile) {
  extern __shared__ short lds[];
  const int td = threadIdx.x;
  const int l = td & 63;
  const int wv = td >> 6;
  const int wm = (wv >> 1) * 64, wn = (wv & 1) * 64;
  const int lr = l & 15;
  const int swzk0 = ((0 + (l >> 4) * 16) ^ ((l & 7) << 4)) >> 1;
  const int swzk1 = ((64 + (l >> 4) * 16) ^ ((l & 7) << 4)) >> 1;
  const int srow = td >> 3;
  const int colsw8 = ((td & 7) ^ (srow & 7)) * 8;

#define K2STAGE(t_, b_)                                                    \
  do {                                                                     \
    gl_lds16(ap[0] + (t_) * 64, lds + (b_) * 16384 + td * 8);              \
    gl_lds16(ap[1] + (t_) * 64, lds + (b_) * 16384 + 2048 + td * 8);       \
    gl_lds16(ap[2] + (t_) * 64, lds + (b_) * 16384 + 4096 + td * 8);       \
    gl_lds16(ap[3] + (t_) * 64, lds + (b_) * 16384 + 6144 + td * 8);       \
    gl_lds16(bp[0] + (t_) * 64, lds + (b_) * 16384 + 8192 + td * 8);       \
    gl_lds16(bp[1] + (t_) * 64, lds + (b_) * 16384 + 10240 + td * 8);      \
    gl_lds16(bp[2] + (t_) * 64, lds + (b_) * 16384 + 12288 + td * 8);      \
    gl_lds16(bp[3] + (t_) * 64, lds + (b_) * 16384 + 14336 + td * 8);      \
  } while (0)
#define LDA2(mf_, swz_) (*(const bf16x8*)&Ah[(unsigned)(((mf_)*16 + lr) * 64) + (swz_)])
#define LDB2(nf_, swz_) (*(const bf16x8*)&Bh[(unsigned)(((nf_)*16 + lr) * 64) + (swz_)])
#define MM2(mf_, a_)                                                                   \
  acc[mf_][0] = __builtin_amdgcn_mfma_f32_16x16x32_bf16(a_, b0, acc[mf_][0], 0, 0, 0); \
  acc[mf_][1] = __builtin_amdgcn_mfma_f32_16x16x32_bf16(a_, b1, acc[mf_][1], 0, 0, 0); \
  acc[mf_][2] = __builtin_amdgcn_mfma_f32_16x16x32_bf16(a_, b2, acc[mf_][2], 0, 0, 0); \
  acc[mf_][3] = __builtin_amdgcn_mfma_f32_16x16x32_bf16(a_, b3, acc[mf_][3], 0, 0, 0)

  const bool isG2 = blockIdx.x < 256;
  const int njob = isG2 ? 1 : 2;
  for (int job = 0; job < njob; ++job) {
    int m_panel = 0, n_panel = 0, m0 = 0, rbeg = 0, rend = 0, bxn = 0, NT, K;
    const short* A;
    const short* Bb;
    bool valid = true;
    if (isG2) {
      const int id = blockIdx.x;
      const int xcd = id & 7, slot = id >> 3;
      n_panel = slot & 7;
      m_panel = xcd * 4 + (slot >> 3);
      A = ubuf;
      K = HS; NT = 32;
      Bb = w2T + (size_t)n_panel * 128 * HS;
    } else {
      const int g = (blockIdx.x - 256) * 2 + job;  // 0..575
      const int ty = g >> 3;
      valid = (ty < ntile[0]);
      bxn = g & 7;
      const int e = valid ? te[ty] : 0;
      m0 = valid ? tm[ty] : 0;
      rbeg = offs[e]; rend = offs[e + 1];
      A = hexpb;
      K = HE; NT = 16;
      Bb = W2eT + ((size_t)e * 1024 + bxn * 128) * 1024;
    }
    if (!valid) continue;

    const short* ap[4];
    const short* bp[4];
#pragma unroll
    for (int u = 0; u < 4; u++) {
      const int trow = u * 32 + srow;
      int grow;
      if (isG2) grow = m_panel * 128 + trow;
      else grow = min(rbeg + m0 + trow, rend - 1);
      ap[u] = A + (size_t)grow * K + colsw8;
      bp[u] = Bb + (size_t)trow * K + colsw8;
    }

    f32x4 acc[4][4] = {};

    K2STAGE(0, 0);
    for (int t = 0; t < NT; ++t) {
      const int p = t & 1, q = p ^ 1;
      const short* Ah = lds + p * 16384 + wm * 64;
      const short* Bh = lds + p * 16384 + 8192 + wn * 64;
      if (t < NT - 1) {
        K2STAGE(t + 1, q);
        asm volatile("s_waitcnt vmcnt(8)" ::: "memory");
      } else {
        asm volatile("s_waitcnt vmcnt(0)" ::: "memory");
      }
      __builtin_amdgcn_s_barrier();
      {
        bf16x8 b0, b1, b2, b3, a0, a1, a2, a3;
        b0 = LDB2(0, swzk0); b1 = LDB2(1, swzk0); b2 = LDB2(2, swzk0); b3 = LDB2(3, swzk0);
        a0 = LDA2(0, swzk0); a1 = LDA2(1, swzk0); a2 = LDA2(2, swzk0); a3 = LDA2(3, swzk0);
        __builtin_amdgcn_s_setprio(1);
        MM2(0, a0); MM2(1, a1); MM2(2, a2); MM2(3, a3);
        __builtin_amdgcn_s_setprio(0);
        b0 = LDB2(0, swzk1); b1 = LDB2(1, swzk1); b2 = LDB2(2, swzk1); b3 = LDB2(3, swzk1);
        a0 = LDA2(0, swzk1); a1 = LDA2(1, swzk1); a2 = LDA2(2, swzk1); a3 = LDA2(3, swzk1);
        __builtin_amdgcn_s_setprio(1);
        MM2(0, a0); MM2(1, a1); MM2(2, a2); MM2(3, a3);
        __builtin_amdgcn_s_setprio(0);
      }
      __builtin_amdgcn_sched_barrier(0);
      __builtin_amdgcn_s_barrier();
    }

    const int rq = (l >> 4) * 4;
    if (isG2) {
#pragma unroll
      for (int mf = 0; mf < 4; mf++)
#pragma unroll
        for (int j = 0; j < 4; j++) {
          const int tok = m_panel * 128 + wm + mf * 16 + rq + j;
          float* Op = out + (size_t)tok * D_MODEL + n_panel * 128 + wn + lr;
#pragma unroll
          for (int nf = 0; nf < 4; nf++) Op[nf * 16] = acc[mf][nf][j];
        }
    } else {
#pragma unroll
      for (int mf = 0; mf < 4; mf++)
#pragma unroll
        for (int j = 0; j < 4; j++) {
          const int gi = rbeg + m0 + wm + mf * 16 + rq + j;
          if (gi < rend) {
            const int slot = perm[gi];
            const float g = gates[slot];
            short* Cp = yb + (size_t)slot * D_MODEL + bxn * 128 + wn + lr;
#pragma unroll
            for (int nf = 0; nf < 4; nf++) Cp[nf * 16] = f2b(g * acc[mf][nf][j]);
          }
        }
    }
  }
#undef K2STAGE
#undef LDA2
#undef LDB2
#undef MM2
}

// ---- final combine: out = (out(shared) + y0 + y1) / 3 ----
__global__ __launch_bounds__(256) void combine_kernel(float* __restrict__ out,
                                                      const short* __restrict__ yb) {
  const float inv3 = 1.0f / 3.0f;
#pragma unroll
  for (int rep = 0; rep < 2; rep++) {
    const int i = (rep * 2048 + blockIdx.x) * 256 + threadIdx.x;
    const int base = i * 4;
    const int tok = base >> 10;
    const int col = base & (D_MODEL - 1);
    float4 s = *(float4*)&out[base];
    const short4 y0 = *(const short4*)&yb[(size_t)(tok * 2) * D_MODEL + col];
    const short4 y1 = *(const short4*)&yb[(size_t)(tok * 2 + 1) * D_MODEL + col];
    s.x = (s.x + b2f(y0.x) + b2f(y1.x)) * inv3;
    s.y = (s.y + b2f(y0.y) + b2f(y1.y)) * inv3;
    s.z = (s.z + b2f(y0.z) + b2f(y1.z)) * inv3;
    s.w = (s.w + b2f(y0.w) + b2f(y1.w)) * inv3;
    *(float4*)&out[base] = s;
  }
}

// ---------------- launch ----------------
extern "C" void kernel_launch(void* const* d_in, const int* in_sizes, int n_in,
                              void* d_out, int out_size, void* d_ws, size_t ws_size,
                              hipStream_t stream) {
  const float* x = (const float*)d_in[0];
  const float* temb = (const float*)d_in[1];
  const float* rw = (const float*)d_in[2];
  const float* rbias = (const float*)d_in[3];
  const float* w1 = (const float*)d_in[4];
  const float* w3 = (const float*)d_in[5];
  const float* w2 = (const float*)d_in[6];
  const float* W1e = (const float*)d_in[7];
  const float* W2e = (const float*)d_in[8];
  float* out = (float*)d_out;

  const size_t MB = 1ull << 20;
  char* w = (char*)d_ws;
  short* xb    = (short*)(w + 0 * MB);
  short* w13I  = (short*)(w + 8 * MB);
  short* w2T   = (short*)(w + 16 * MB);
  short* W1eT  = (short*)(w + 20 * MB);
  short* W2eT  = (short*)(w + 36 * MB);
  short* ubuf  = (short*)(w + 52 * MB);
  short* hexpb = (short*)(w + 68 * MB);
  short* yb    = (short*)(w + 84 * MB);
  float* gates = (float*)(w + 100 * MB);
  int* topk    = (int*)(w + 100 * MB + 32 * 1024);
  int* perm    = (int*)(w + 100 * MB + 64 * 1024);
  int* meta    = (int*)(w + 100 * MB + 96 * 1024);
  int* offs    = meta;
  int* te      = meta + 16;
  int* tm      = meta + 128;
  int* ntile   = meta + 256;

  hipFuncSetAttribute((const void*)&moe_k1,
                      hipFuncAttributeMaxDynamicSharedMemorySize, 65536);
  hipFuncSetAttribute((const void*)&moe_k2,
                      hipFuncAttributeMaxDynamicSharedMemorySize, 65536);

  // prep
  tr_all<<<2816, 256, 0, stream>>>(w1, w3, w2, W1e, W2e, w13I, w2T, W1eT, W2eT);
  router_kernel<<<NTOK / 4, 256, 0, stream>>>(x, temb, rw, rbias, xb, topk, gates);
  group_kernel<<<1, 1024, 0, stream>>>(topk, perm, offs, te, tm, ntile);

  // kernel-1: static persistent 800 blocks x 2 jobs (G1 1024 + GG1 576)
  moe_k1<<<800, 256, 65536, stream>>>(xb, w13I, W1eT, ubuf, hexpb, perm, offs,
                                      te, tm, ntile);

  // kernel-2: statically balanced 544 blocks (256x G2 + 288x 2xGG2)
  moe_k2<<<544, 256, 65536, stream>>>(ubuf, w2T, hexpb, W2eT, out, yb, perm,
                                      offs, gates, te, tm, ntile);

  // combine
  combine_kernel<<<2048, 256, 0, stream>>>(out, yb);
}

// Round 21
// 207.790 us; speedup vs baseline: 2.1907x; 1.0774x over previous
//
#include <hip/hip_runtime.h>
#include <hip/hip_bf16.h>
#include <math.h>

#define D_MODEL 1024
#define HS 2048
#define HE 1024
#define NEXP 8
#define NTOK 4096
#define NSLOT 8192

typedef __attribute__((ext_vector_type(4))) float f32x4;
typedef __attribute__((ext_vector_type(8))) short bf16x8;

__device__ __forceinline__ short f2b(float f) {
  __hip_bfloat16 h = __float2bfloat16(f);
  return *reinterpret_cast<short*>(&h);
}
__device__ __forceinline__ float b2f(short s) {
  return __bfloat162float(*reinterpret_cast<__hip_bfloat16*>(&s));
}

__device__ __forceinline__ void gl_lds16(const short* g, short* l) {
  __builtin_amdgcn_global_load_lds(
      (const __attribute__((address_space(1))) void*)g,
      (__attribute__((address_space(3))) void*)l, 16, 0, 0);
}

// ---------------- merged transpose prep (one tile per block, 5632 blocks) ----
__device__ __forceinline__ void tr_tile(const float* __restrict__ in,
                                        short* __restrict__ out, int R, int C,
                                        int bx, int by, int bz, int rmap,
                                        float (*tile)[69], int t) {
  const int c0 = bx * 64;
  const int r0 = by * 64;
  const size_t bo = (size_t)bz * R * C;
  const int lr = t >> 4;
  const int lc4 = (t & 15) * 4;
#pragma unroll
  for (int i = 0; i < 4; i++) {
    const float4 v = *(const float4*)&in[bo + (size_t)(r0 + lr + i * 16) * C + c0 + lc4];
    tile[lc4 + 0][lr + i * 16] = v.x;
    tile[lc4 + 1][lr + i * 16] = v.y;
    tile[lc4 + 2][lr + i * 16] = v.z;
    tile[lc4 + 3][lr + i * 16] = v.w;
  }
  __syncthreads();
#pragma unroll
  for (int i = 0; i < 4; i++) {
    const int oc = (t >> 4) + i * 16;
    const int or4 = (t & 15) * 4;
    short4 o;
    o.x = f2b(tile[oc][or4 + 0]);
    o.y = f2b(tile[oc][or4 + 1]);
    o.z = f2b(tile[oc][or4 + 2]);
    o.w = f2b(tile[oc][or4 + 3]);
    const int c = c0 + oc;
    size_t orow;
    if (rmap == 0) orow = bo + (size_t)c * R;
    else orow = (size_t)((c >> 5) * 64 + (rmap == 2 ? 32 : 0) + (c & 31)) * R;
    *(short4*)&out[orow + r0 + or4] = o;
  }
}

__global__ __launch_bounds__(256) void tr_all(
    const float* __restrict__ w1, const float* __restrict__ w3,
    const float* __restrict__ w2, const float* __restrict__ W1e,
    const float* __restrict__ W2e, short* __restrict__ w13I,
    short* __restrict__ w2T, short* __restrict__ W1eT, short* __restrict__ W2eT) {
  __shared__ float tile[64][69];
  const int id = blockIdx.x;
  const int t = threadIdx.x;
  if (id < 1024) {
    const int z = id >> 9, rem = id & 511;
    tr_tile(z ? w3 : w1, w13I, D_MODEL, HS, rem & 31, rem >> 5, 0, z ? 2 : 1, tile, t);
  } else if (id < 1536) {
    const int rem = id - 1024;
    tr_tile(w2, w2T, HS, D_MODEL, rem & 15, rem >> 4, 0, 0, tile, t);
  } else {
    const int rem = id - 1536;
    const int z = rem >> 8, r2 = rem & 255;
    if (z < 8)
      tr_tile(W1e, W1eT, D_MODEL, HE, r2 & 15, r2 >> 4, z, 0, tile, t);
    else
      tr_tile(W2e, W2eT, HE, D_MODEL, r2 & 15, r2 >> 4, z - 8, 0, tile, t);
  }
}

// ------- router + x->bf16 convert fused -------
__global__ __launch_bounds__(256) void router_kernel(
    const float* __restrict__ x, const float* __restrict__ temb,
    const float* __restrict__ rw, const float* __restrict__ rbias,
    short* __restrict__ xb, int* __restrict__ topk, float* __restrict__ gates) {
  const int t = (blockIdx.x * 256 + threadIdx.x) >> 6;
  const int lane = threadIdx.x & 63;
  const float* xr = x + (size_t)t * D_MODEL;
  const float* tr = temb + (size_t)(t >> 10) * D_MODEL;  // T=1024
  float acc[NEXP] = {};
#pragma unroll
  for (int i = 0; i < 4; i++) {
    const int j = i * 256 + lane * 4;
    const float4 xv = *(const float4*)&xr[j];
    const float4 tv = *(const float4*)&tr[j];
    short4 o;
    o.x = f2b(xv.x); o.y = f2b(xv.y); o.z = f2b(xv.z); o.w = f2b(xv.w);
    *(short4*)&xb[(size_t)t * D_MODEL + j] = o;
    const float* wx = rw + (size_t)j * NEXP;
    const float* wt = rw + (size_t)(D_MODEL + j) * NEXP;
    const float xa[4] = {xv.x, xv.y, xv.z, xv.w};
    const float ta[4] = {tv.x, tv.y, tv.z, tv.w};
#pragma unroll
    for (int u = 0; u < 4; u++)
#pragma unroll
      for (int e = 0; e < NEXP; e++)
        acc[e] += xa[u] * wx[u * NEXP + e] + ta[u] * wt[u * NEXP + e];
  }
#pragma unroll
  for (int off = 32; off; off >>= 1)
#pragma unroll
    for (int e = 0; e < NEXP; e++) acc[e] += __shfl_xor(acc[e], off);
  if (lane == 0) {
    float s[NEXP], sel[NEXP];
#pragma unroll
    for (int e = 0; e < NEXP; e++) {
      s[e] = 1.f / (1.f + expf(-acc[e]));
      sel[e] = s[e] + rbias[e];
    }
    int i0 = 0;
#pragma unroll
    for (int e = 1; e < NEXP; e++) if (sel[e] > sel[i0]) i0 = e;
    int i1 = (i0 == 0) ? 1 : 0;
#pragma unroll
    for (int e = 0; e < NEXP; e++) if (e != i0 && sel[e] > sel[i1]) i1 = e;
    float s0 = s[i0], s1 = s[i1], den = s0 + s1;
    float g0, g1;
    if (den > 1e-9f) { g0 = s0 / (den + 1e-9f); g1 = s1 / (den + 1e-9f); }
    else { g0 = 0.5f; g1 = 0.5f; }
    topk[t * 2] = i0; topk[t * 2 + 1] = i1;
    gates[t * 2] = g0; gates[t * 2 + 1] = g1;
  }
}

// ------- grouping: hist + scan + fill + BM=128 tile table (ntile <= 72) ------
__global__ __launch_bounds__(1024) void group_kernel(const int* __restrict__ topk,
                                                     int* __restrict__ perm,
                                                     int* __restrict__ offs,
                                                     int* __restrict__ te,
                                                     int* __restrict__ tm,
                                                     int* __restrict__ ntile) {
  __shared__ int cnt[NEXP], cur[NEXP];
  const int t = threadIdx.x;
  if (t < NEXP) cnt[t] = 0;
  __syncthreads();
  int mye[8];
#pragma unroll
  for (int i = 0; i < 8; i++) {
    mye[i] = topk[i * 1024 + t];
    atomicAdd(&cnt[mye[i]], 1);
  }
  __syncthreads();
  if (t == 0) {
    int a = 0;
    for (int e = 0; e < NEXP; e++) { offs[e] = a; cur[e] = a; a += cnt[e]; }
    offs[NEXP] = a;
    int nt = 0;
    for (int e = 0; e < NEXP; e++)
      for (int m0 = 0; m0 < cnt[e]; m0 += 128) { te[nt] = e; tm[nt] = m0; nt++; }
    ntile[0] = nt;  // <= 72
  }
  __syncthreads();
#pragma unroll
  for (int i = 0; i < 8; i++) {
    int pos = atomicAdd(&cur[mye[i]], 1);
    perm[pos] = i * 1024 + t;
  }
}

// ====== KERNEL-1: static persistent 2-job (R18-measured-best). Jobs 0..1599 ======
__global__ __launch_bounds__(256, 2) void moe_k1(
    const short* __restrict__ xb, const short* __restrict__ w13I,
    const short* __restrict__ W1eT, short* __restrict__ ubuf,
    short* __restrict__ hexpb, const int* __restrict__ perm,
    const int* __restrict__ offs, const int* __restrict__ te,
    const int* __restrict__ tm, const int* __restrict__ ntile) {
  extern __shared__ short lds[];
  const int td = threadIdx.x;

  const int l = td & 63;
  const int wv = td >> 6;
  const int wm = (wv >> 1) * 64, wn = (wv & 1) * 64;
  const int lr = l & 15;
  const int swzk0 = ((0 + (l >> 4) * 16) ^ ((l & 7) << 4)) >> 1;
  const int swzk1 = ((64 + (l >> 4) * 16) ^ ((l & 7) << 4)) >> 1;
  const int srow = td >> 3;
  const int colsw8 = ((td & 7) ^ (srow & 7)) * 8;

#define K1STAGE(t_, b_)                                                    \
  do {                                                                     \
    gl_lds16(ap[0] + (t_) * 64, lds + (b_) * 16384 + td * 8);              \
    gl_lds16(ap[1] + (t_) * 64, lds + (b_) * 16384 + 2048 + td * 8);       \
    gl_lds16(ap[2] + (t_) * 64, lds + (b_) * 16384 + 4096 + td * 8);       \
    gl_lds16(ap[3] + (t_) * 64, lds + (b_) * 16384 + 6144 + td * 8);       \
    gl_lds16(bp[0] + (t_) * 64, lds + (b_) * 16384 + 8192 + td * 8);       \
    gl_lds16(bp[1] + (t_) * 64, lds + (b_) * 16384 + 10240 + td * 8);      \
    gl_lds16(bp[2] + (t_) * 64, lds + (b_) * 16384 + 12288 + td * 8);      \
    gl_lds16(bp[3] + (t_) * 64, lds + (b_) * 16384 + 14336 + td * 8);      \
  } while (0)
#define LDA1(mf_, swz_) (*(const bf16x8*)&Ah[(unsigned)(((mf_)*16 + lr) * 64) + (swz_)])
#define LDB1(nf_, swz_) (*(const bf16x8*)&Bh[(unsigned)(((nf_)*16 + lr) * 64) + (swz_)])
#define MM1(mf_, a_)                                                                   \
  acc[mf_][0] = __builtin_amdgcn_mfma_f32_16x16x32_bf16(a_, b0, acc[mf_][0], 0, 0, 0); \
  acc[mf_][1] = __builtin_amdgcn_mfma_f32_16x16x32_bf16(a_, b1, acc[mf_][1], 0, 0, 0); \
  acc[mf_][2] = __builtin_amdgcn_mfma_f32_16x16x32_bf16(a_, b2, acc[mf_][2], 0, 0, 0); \
  acc[mf_][3] = __builtin_amdgcn_mfma_f32_16x16x32_bf16(a_, b3, acc[mf_][3], 0, 0, 0)

  for (int job = 0; job < 2; ++job) {
    const int id = blockIdx.x + job * 800;
    const bool isG1 = id < 1024;
    int m_panel = 0, n_panel = 0, m0 = 0, rbeg = 0, rend = 0, bxn = 0;
    const short* Bb;
    bool valid = true;
    if (isG1) {
      const int xcd = id & 7, w = id >> 3;
      n_panel = xcd * 4 + (w >> 5);  // 32 n-panels (w13I 4096 rows / 128)
      m_panel = w & 31;
      Bb = w13I + (size_t)n_panel * 128 * 1024;
    } else {
      const int g = id - 1024;
      const int ty = g >> 3;
      valid = (ty < ntile[0]);
      bxn = g & 7;
      const int e = valid ? te[ty] : 0;
      m0 = valid ? tm[ty] : 0;
      rbeg = offs[e]; rend = offs[e + 1];
      Bb = W1eT + ((size_t)e * 1024 + bxn * 128) * 1024;
    }
    if (!valid) continue;  // uniform across block

    const short* ap[4];
    const short* bp[4];
#pragma unroll
    for (int u = 0; u < 4; u++) {
      const int trow = u * 32 + srow;
      int grow;
      if (isG1) grow = m_panel * 128 + trow;
      else grow = perm[min(rbeg + m0 + trow, rend - 1)] >> 1;
      ap[u] = xb + (size_t)grow * 1024 + colsw8;
      bp[u] = Bb + (size_t)trow * 1024 + colsw8;
    }

    f32x4 acc[4][4] = {};

    K1STAGE(0, 0);
    for (int t = 0; t < 16; ++t) {
      const int p = t & 1, q = p ^ 1;
      const short* Ah = lds + p * 16384 + wm * 64;
      const short* Bh = lds + p * 16384 + 8192 + wn * 64;
      if (t < 15) {
        K1STAGE(t + 1, q);
        asm volatile("s_waitcnt vmcnt(8)" ::: "memory");
      } else {
        asm volatile("s_waitcnt vmcnt(0)" ::: "memory");
      }
      __builtin_amdgcn_s_barrier();
      {
        bf16x8 b0, b1, b2, b3, a0, a1, a2, a3;
        b0 = LDB1(0, swzk0); b1 = LDB1(1, swzk0); b2 = LDB1(2, swzk0); b3 = LDB1(3, swzk0);
        a0 = LDA1(0, swzk0); a1 = LDA1(1, swzk0); a2 = LDA1(2, swzk0); a3 = LDA1(3, swzk0);
        __builtin_amdgcn_s_setprio(1);
        MM1(0, a0); MM1(1, a1); MM1(2, a2); MM1(3, a3);
        __builtin_amdgcn_s_setprio(0);
        b0 = LDB1(0, swzk1); b1 = LDB1(1, swzk1); b2 = LDB1(2, swzk1); b3 = LDB1(3, swzk1);
        a0 = LDA1(0, swzk1); a1 = LDA1(1, swzk1); a2 = LDA1(2, swzk1); a3 = LDA1(3, swzk1);
        __builtin_amdgcn_s_setprio(1);
        MM1(0, a0); MM1(1, a1); MM1(2, a2); MM1(3, a3);
        __builtin_amdgcn_s_setprio(0);
      }
      __builtin_amdgcn_sched_barrier(0);
      __builtin_amdgcn_s_barrier();
    }

    const int rq = (l >> 4) * 4;
    if (isG1) {
#pragma unroll
      for (int mf = 0; mf < 4; mf++)
#pragma unroll
        for (int j = 0; j < 4; j++) {
          const int row = m_panel * 128 + wm + mf * 16 + rq + j;
          short* Up = ubuf + (size_t)row * HS + n_panel * 64 + (wn >> 1) + lr;
#pragma unroll
          for (int nf = 0; nf < 2; nf++) {
            const float a = acc[mf][nf][j];
            const float b = acc[mf][nf + 2][j];
            Up[nf * 16] = f2b(a / (1.f + expf(-a)) * b);
          }
        }
    } else {
#pragma unroll
      for (int mf = 0; mf < 4; mf++)
#pragma unroll
        for (int j = 0; j < 4; j++) {
          const int gi = rbeg + m0 + wm + mf * 16 + rq + j;
          if (gi < rend) {
            short* Cp = hexpb + (size_t)gi * HE + bxn * 128 + wn + lr;
#pragma unroll
            for (int nf = 0; nf < 4; nf++) {
              const float v = acc[mf][nf][j];
              Cp[nf * 16] = f2b(0.5f * v * (1.0f + erff(v * 0.70710678118654752f)));
            }
          }
        }
    }
  }
#undef K1STAGE
#undef LDA1
#undef LDB1
#undef MM1
}

// ====== KERNEL-2: static persistent 2-job (R18-measured-best). Jobs 0..831 ======
__global__ __launch_bounds__(256, 2) void moe_k2(
    const short* __restrict__ ubuf, const short* __restrict__ w2T,
    const short* __restrict__ hexpb, const short* __restrict__ W2eT,
    float* __restrict__ out, short* __restrict__ yb,
    const int* __restrict__ perm, const int* __restrict__ offs,
    const float* __restrict__ gates, const int* __restrict__ te,
    const int* __restrict__ tm, const int* __restrict__ ntile) {
  extern __shared__ short lds[];
  const int td = threadIdx.x;
  const int l = td & 63;
  const int wv = td >> 6;
  const int wm = (wv >> 1) * 64, wn = (wv & 1) * 64;
  const int lr = l & 15;
  const int swzk0 = ((0 + (l >> 4) * 16) ^ ((l & 7) << 4)) >> 1;
  const int swzk1 = ((64 + (l >> 4) * 16) ^ ((l & 7) << 4)) >> 1;
  const int srow = td >> 3;
  const int colsw8 = ((td & 7) ^ (srow & 7)) * 8;

#define K2STAGE(t_, b_)                                                    \
  do {                                                                     \
    gl_lds16(ap[0] + (t_) * 64, lds + (b_) * 16384 + td * 8);              \
    gl_lds16(ap[1] + (t_) * 64, lds + (b_) * 16384 + 2048 + td * 8);       \
    gl_lds16(ap[2] + (t_) * 64, lds + (b_) * 16384 + 4096 + td * 8);       \
    gl_lds16(ap[3] + (t_) * 64, lds + (b_) * 16384 + 6144 + td * 8);       \
    gl_lds16(bp[0] + (t_) * 64, lds + (b_) * 16384 + 8192 + td * 8);       \
    gl_lds16(bp[1] + (t_) * 64, lds + (b_) * 16384 + 10240 + td * 8);      \
    gl_lds16(bp[2] + (t_) * 64, lds + (b_) * 16384 + 12288 + td * 8);      \
    gl_lds16(bp[3] + (t_) * 64, lds + (b_) * 16384 + 14336 + td * 8);      \
  } while (0)
#define LDA2(mf_, swz_) (*(const bf16x8*)&Ah[(unsigned)(((mf_)*16 + lr) * 64) + (swz_)])
#define LDB2(nf_, swz_) (*(const bf16x8*)&Bh[(unsigned)(((nf_)*16 + lr) * 64) + (swz_)])
#define MM2(mf_, a_)                                                                   \
  acc[mf_][0] = __builtin_amdgcn_mfma_f32_16x16x32_bf16(a_, b0, acc[mf_][0], 0, 0, 0); \
  acc[mf_][1] = __builtin_amdgcn_mfma_f32_16x16x32_bf16(a_, b1, acc[mf_][1], 0, 0, 0); \
  acc[mf_][2] = __builtin_amdgcn_mfma_f32_16x16x32_bf16(a_, b2, acc[mf_][2], 0, 0, 0); \
  acc[mf_][3] = __builtin_amdgcn_mfma_f32_16x16x32_bf16(a_, b3, acc[mf_][3], 0, 0, 0)

  for (int job = 0; job < 2; ++job) {
    const int id = blockIdx.x + job * 416;
    const bool isG2 = id < 256;
    int m_panel = 0, n_panel = 0, m0 = 0, rbeg = 0, rend = 0, bxn = 0, NT, K;
    const short* A;
    const short* Bb;
    bool valid = true;
    if (isG2) {
      const int xcd = id & 7, slot = id >> 3;
      n_panel = slot & 7;
      m_panel = xcd * 4 + (slot >> 3);
      A = ubuf;
      K = HS; NT = 32;
      Bb = w2T + (size_t)n_panel * 128 * HS;
    } else {
      const int g = id - 256;
      const int ty = g >> 3;
      valid = (ty < ntile[0]);
      bxn = g & 7;
      const int e = valid ? te[ty] : 0;
      m0 = valid ? tm[ty] : 0;
      rbeg = offs[e]; rend = offs[e + 1];
      A = hexpb;
      K = HE; NT = 16;
      Bb = W2eT + ((size_t)e * 1024 + bxn * 128) * 1024;
    }
    if (!valid) continue;

    const short* ap[4];
    const short* bp[4];
#pragma unroll
    for (int u = 0; u < 4; u++) {
      const int trow = u * 32 + srow;
      int grow;
      if (isG2) grow = m_panel * 128 + trow;
      else grow = min(rbeg + m0 + trow, rend - 1);
      ap[u] = A + (size_t)grow * K + colsw8;
      bp[u] = Bb + (size_t)trow * K + colsw8;
    }

    f32x4 acc[4][4] = {};

    K2STAGE(0, 0);
    for (int t = 0; t < NT; ++t) {
      const int p = t & 1, q = p ^ 1;
      const short* Ah = lds + p * 16384 + wm * 64;
      const short* Bh = lds + p * 16384 + 8192 + wn * 64;
      if (t < NT - 1) {
        K2STAGE(t + 1, q);
        asm volatile("s_waitcnt vmcnt(8)" ::: "memory");
      } else {
        asm volatile("s_waitcnt vmcnt(0)" ::: "memory");
      }
      __builtin_amdgcn_s_barrier();
      {
        bf16x8 b0, b1, b2, b3, a0, a1, a2, a3;
        b0 = LDB2(0, swzk0); b1 = LDB2(1, swzk0); b2 = LDB2(2, swzk0); b3 = LDB2(3, swzk0);
        a0 = LDA2(0, swzk0); a1 = LDA2(1, swzk0); a2 = LDA2(2, swzk0); a3 = LDA2(3, swzk0);
        __builtin_amdgcn_s_setprio(1);
        MM2(0, a0); MM2(1, a1); MM2(2, a2); MM2(3, a3);
        __builtin_amdgcn_s_setprio(0);
        b0 = LDB2(0, swzk1); b1 = LDB2(1, swzk1); b2 = LDB2(2, swzk1); b3 = LDB2(3, swzk1);
        a0 = LDA2(0, swzk1); a1 = LDA2(1, swzk1); a2 = LDA2(2, swzk1); a3 = LDA2(3, swzk1);
        __builtin_amdgcn_s_setprio(1);
        MM2(0, a0); MM2(1, a1); MM2(2, a2); MM2(3, a3);
        __builtin_amdgcn_s_setprio(0);
      }
      __builtin_amdgcn_sched_barrier(0);
      __builtin_amdgcn_s_barrier();
    }

    const int rq = (l >> 4) * 4;
    if (isG2) {
#pragma unroll
      for (int mf = 0; mf < 4; mf++)
#pragma unroll
        for (int j = 0; j < 4; j++) {
          const int tok = m_panel * 128 + wm + mf * 16 + rq + j;
          float* Op = out + (size_t)tok * D_MODEL + n_panel * 128 + wn + lr;
#pragma unroll
          for (int nf = 0; nf < 4; nf++) Op[nf * 16] = acc[mf][nf][j];
        }
    } else {
#pragma unroll
      for (int mf = 0; mf < 4; mf++)
#pragma unroll
        for (int j = 0; j < 4; j++) {
          const int gi = rbeg + m0 + wm + mf * 16 + rq + j;
          if (gi < rend) {
            const int slot = perm[gi];
            const float g = gates[slot];
            short* Cp = yb + (size_t)slot * D_MODEL + bxn * 128 + wn + lr;
#pragma unroll
            for (int nf = 0; nf < 4; nf++) Cp[nf * 16] = f2b(g * acc[mf][nf][j]);
          }
        }
    }
  }
#undef K2STAGE
#undef LDA2
#undef LDB2
#undef MM2
}

// ---- final combine: out = (out(shared) + y0 + y1) / 3 ----
__global__ __launch_bounds__(256) void combine_kernel(float* __restrict__ out,
                                                      const short* __restrict__ yb) {
  const float inv3 = 1.0f / 3.0f;
#pragma unroll
  for (int rep = 0; rep < 2; rep++) {
    const int i = (rep * 2048 + blockIdx.x) * 256 + threadIdx.x;
    const int base = i * 4;
    const int tok = base >> 10;
    const int col = base & (D_MODEL - 1);
    float4 s = *(float4*)&out[base];
    const short4 y0 = *(const short4*)&yb[(size_t)(tok * 2) * D_MODEL + col];
    const short4 y1 = *(const short4*)&yb[(size_t)(tok * 2 + 1) * D_MODEL + col];
    s.x = (s.x + b2f(y0.x) + b2f(y1.x)) * inv3;
    s.y = (s.y + b2f(y0.y) + b2f(y1.y)) * inv3;
    s.z = (s.z + b2f(y0.z) + b2f(y1.z)) * inv3;
    s.w = (s.w + b2f(y0.w) + b2f(y1.w)) * inv3;
    *(float4*)&out[base] = s;
  }
}

// ---------------- launch ----------------
extern "C" void kernel_launch(void* const* d_in, const int* in_sizes, int n_in,
                              void* d_out, int out_size, void* d_ws, size_t ws_size,
                              hipStream_t stream) {
  const float* x = (const float*)d_in[0];
  const float* temb = (const float*)d_in[1];
  const float* rw = (const float*)d_in[2];
  const float* rbias = (const float*)d_in[3];
  const float* w1 = (const float*)d_in[4];
  const float* w3 = (const float*)d_in[5];
  const float* w2 = (const float*)d_in[6];
  const float* W1e = (const float*)d_in[7];
  const float* W2e = (const float*)d_in[8];
  float* out = (float*)d_out;

  const size_t MB = 1ull << 20;
  char* w = (char*)d_ws;
  short* xb    = (short*)(w + 0 * MB);
  short* w13I  = (short*)(w + 8 * MB);
  short* w2T   = (short*)(w + 16 * MB);
  short* W1eT  = (short*)(w + 20 * MB);
  short* W2eT  = (short*)(w + 36 * MB);
  short* ubuf  = (short*)(w + 52 * MB);
  short* hexpb = (short*)(w + 68 * MB);
  short* yb    = (short*)(w + 84 * MB);
  float* gates = (float*)(w + 100 * MB);
  int* topk    = (int*)(w + 100 * MB + 32 * 1024);
  int* perm    = (int*)(w + 100 * MB + 64 * 1024);
  int* meta    = (int*)(w + 100 * MB + 96 * 1024);
  int* offs    = meta;
  int* te      = meta + 16;
  int* tm      = meta + 128;
  int* ntile   = meta + 256;

  hipFuncSetAttribute((const void*)&moe_k1,
                      hipFuncAttributeMaxDynamicSharedMemorySize, 65536);
  hipFuncSetAttribute((const void*)&moe_k2,
                      hipFuncAttributeMaxDynamicSharedMemorySize, 65536);

  // prep
  tr_all<<<5632, 256, 0, stream>>>(w1, w3, w2, W1e, W2e, w13I, w2T, W1eT, W2eT);
  router_kernel<<<NTOK / 4, 256, 0, stream>>>(x, temb, rw, rbias, xb, topk, gates);
  group_kernel<<<1, 1024, 0, stream>>>(topk, perm, offs, te, tm, ntile);

  // kernel-1: static persistent 800 blocks x 2 jobs (G1 1024 + GG1 576)
  moe_k1<<<800, 256, 65536, stream>>>(xb, w13I, W1eT, ubuf, hexpb, perm, offs,
                                      te, tm, ntile);

  // kernel-2: static persistent 416 blocks x 2 jobs (G2 256 + GG2 576)
  moe_k2<<<416, 256, 65536, stream>>>(ubuf, w2T, hexpb, W2eT, out, yb, perm,
                                      offs, gates, te, tm, ntile);

  // combine
  combine_kernel<<<2048, 256, 0, stream>>>(out, yb);
}